// Round 16
// baseline (1668.002 us; speedup 1.0000x reference)
//
#include <hip/hip_runtime.h>

// ---------------- constants ----------------
constexpr int NT = 64;     // timesteps
constexpr int NB = 64;     // batch
constexpr int NV = 32000;  // vocab
constexpr int NE = 512;    // embed
constexpr int NH = 512;    // hidden
// wgs: [0,32) l0A (r:0-15, z:16-31) | [32,64) l1A | [64,80) l0B | [80,96) l1B | [96,256) gemm
constexpr int NPAIR = 16 * 250;   // gemm steals: (bm-pair, bn)

constexpr size_t SZ_OW  = (size_t)NV * NE;
constexpr size_t SZ_XE  = (size_t)NT * NB * NE;
constexpr size_t SZ_H   = (size_t)NB * NH;
constexpr size_t LOGITS = (size_t)NT * NB * NV;

typedef float f32x4 __attribute__((ext_vector_type(4)));
typedef int   i32x4 __attribute__((ext_vector_type(4)));
typedef short bf16x8 __attribute__((ext_vector_type(8)));
typedef short s16x4 __attribute__((ext_vector_type(4)));
typedef _Float16 f16x8 __attribute__((ext_vector_type(8)));

// ---------------- helpers ----------------
__device__ __forceinline__ unsigned short f2bf(float x) {
  unsigned u = __float_as_uint(x);
  u += 0x7FFFu + ((u >> 16) & 1u);            // RNE
  return (unsigned short)(u >> 16);
}
__device__ __forceinline__ float bf2f(unsigned short s) {
  return __uint_as_float(((unsigned)s) << 16);
}
__device__ __forceinline__ void split2(float v, short* hi, short* lo) {
  unsigned short h = f2bf(v);
  *hi = (short)h;
  *lo = (short)f2bf(v - bf2f(h));
}
__device__ __forceinline__ f32x4 mma_bf16(bf16x8 a, bf16x8 b, f32x4 c) {
  return __builtin_amdgcn_mfma_f32_16x16x32_bf16(a, b, c, 0, 0, 0);
}
__device__ __forceinline__ f32x4 mma_f16(f16x8 a, f16x8 b, f32x4 c) {
  return __builtin_amdgcn_mfma_f32_16x16x32_f16(a, b, c, 0, 0, 0);
}
__device__ __forceinline__ float fast_sigmoid(float x) {
  return __builtin_amdgcn_rcpf(1.0f + __expf(-x));
}
__device__ __forceinline__ float fast_tanh(float x) {
  return 1.0f - 2.0f * __builtin_amdgcn_rcpf(1.0f + __expf(2.0f * x));
}

// write-through-to-LLC stores (LLC/MALL = chip-level coherence point)
__device__ __forceinline__ void st_sc32u(unsigned* p, unsigned v) {
  asm volatile("global_store_dword %0, %1, off sc0 sc1" :: "v"(p), "v"(v) : "memory");
}
__device__ __forceinline__ void st_sc128(void* p, i32x4 v) {
  asm volatile("global_store_dwordx4 %0, %1, off sc0 sc1" :: "v"(p), "v"(v) : "memory");
}
__device__ __forceinline__ void st_nt(float* p, float v) {
  asm volatile("global_store_dword %0, %1, off nt" :: "v"(p), "v"(v) : "memory");
}
__device__ __forceinline__ unsigned ld_sc32u(const unsigned* p) {
  unsigned v;
  asm volatile("global_load_dword %0, %1, off sc0 sc1\n\ts_waitcnt vmcnt(0)"
               : "=v"(v) : "v"(p) : "memory");
  return v;
}

// per-lane wave poll: every lane has its own (fp, thr); exits when ALL satisfied
__device__ __forceinline__ void wave_poll(const unsigned* fp, unsigned thr) {
  while (!__all((int)(ld_sc32u(fp) >= thr))) {}
}
// per-WAVE publish: drain own stores, lane 0 sets flag (NO workgroup barrier)
__device__ __forceinline__ void wpublish(unsigned* flags, int slot, unsigned val, int lane) {
  asm volatile("s_waitcnt vmcnt(0)" ::: "memory");
  if (lane == 0) st_sc32u(&flags[(size_t)slot * 32], val);
}

// ---------------- prep ----------------
__global__ void k_prep(
    const float* __restrict__ outw, const int* __restrict__ toks,
    const float* __restrict__ emb, const float* __restrict__ hid,
    _Float16* OWf, short* XeHi, short* XeLo,
    short* X1Hi, short* X1Lo, short* h0Hi, short* h0Lo) {
  const size_t stride = (size_t)gridDim.x * blockDim.x;
  const size_t N1 = SZ_OW, N2 = N1 + SZ_XE, N3 = N2 + SZ_H, N4 = N3 + SZ_H;
  for (size_t x = (size_t)blockIdx.x * blockDim.x + threadIdx.x; x < N4; x += stride) {
    if (x < N1) {
      OWf[x] = (_Float16)outw[x];
    } else if (x < N2) {
      size_t p = x - N1;
      size_t r = p >> 9, c = p & 511u;
      int tok = toks[r];
      float v = emb[(size_t)tok * 512 + c];
      short hi, lo; split2(v, &hi, &lo);
      XeHi[p] = hi; XeLo[p] = lo;
    } else if (x < N3) {
      size_t p = x - N2;
      short hi, lo; split2(hid[p], &hi, &lo);
      h0Hi[p] = hi; h0Lo[p] = lo;
    } else {
      size_t p = x - N3;
      short hi, lo; split2(hid[SZ_H + p], &hi, &lo);
      X1Hi[p] = hi; X1Lo[p] = lo;
    }
  }
}

// ---------------- per-wave MMA: 16 k-steps (512 k) of a 16x16 tile, full in-wave ----
// acts row-major [64][512]; r0 = lane's act row; wrow = lane's weight row in LDS slice.
__device__ __forceinline__ void waveMMA16(
    const short* __restrict__ aH, const short* __restrict__ aL,
    int r0, int wkb, const short* lsHi_, const short* lsLo_, int wrow,
    f32x4 (&accH)[2], f32x4 (&accL)[2], int lq) {
#pragma unroll
  for (int blk = 0; blk < 16; blk += 8) {
    bf16x8 ah[8], al[8];
#pragma unroll
    for (int i = 0; i < 8; ++i) {
      const int ka = (blk + i) * 32 + lq * 8;
      ah[i] = *(const bf16x8*)&aH[r0 * 512 + ka];
      al[i] = *(const bf16x8*)&aL[r0 * 512 + ka];
    }
#pragma unroll
    for (int i = 0; i < 8; ++i) {
      const int kg = wkb + (blk + i) * 32 + lq * 8;
      const int e = (wrow * 1024 + kg) ^ ((wrow & 7) << 3);
      bf16x8 bh = *(const bf16x8*)&lsHi_[e];
      bf16x8 bl = *(const bf16x8*)&lsLo_[e];
      const int p = i & 1;
      accH[p] = mma_bf16(ah[i], bh, accH[p]);
      accL[p] = mma_bf16(al[i], bh, accL[p]);
      accL[p] = mma_bf16(ah[i], bl, accL[p]);
    }
  }
}

// weight staging: 32 rows x 1024 k as split bf16 hi/lo, XOR-swizzled (per wg, once)
__device__ __forceinline__ void stage_weights(
    short* lsHi, short* lsLo, const float* srcBase0, const float* srcBase1,
    int jc, int tid) {
  for (int i = tid; i < 8192; i += 512) {
    const int j = i >> 8;
    const int k4 = (i & 255) << 2;
    const int g = jc + j;
    const float* src = (srcBase1 && g >= 512)
        ? (srcBase1 + (size_t)(g - 512) * 1024 + k4)
        : (srcBase0 + (size_t)g * 1024 + k4);
    f32x4 v = *(const f32x4*)src;
    s16x4 h4, l4;
#pragma unroll
    for (int q = 0; q < 4; ++q) { short hi, lo; split2(v[q], &hi, &lo); h4[q] = hi; l4[q] = lo; }
    const int els = (j * 1024 + k4) ^ ((j & 7) << 3);
    *(s16x4*)&lsHi[els] = h4;
    *(s16x4*)&lsLo[els] = l4;
  }
}

// per-wave transposed hi/lo store: tile 16x16 -> one st_sc128 per lane (coalesced)
__device__ __forceinline__ void wave_store16(
    const short* scrH, const short* scrL,
    short* gHi, short* gLo, int rt, int colBase, int lane) {
  asm volatile("s_waitcnt lgkmcnt(0)" ::: "memory");
  const int rr = lane >> 2, cc = lane & 3;
  i32x4 v;
  if (cc < 2) v = *(const i32x4*)&scrH[rr * 16 + cc * 8];
  else        v = *(const i32x4*)&scrL[rr * 16 + (cc - 2) * 8];
  short* dst = (cc < 2 ? gHi : gLo) + (size_t)(rt * 16 + rr) * 512 + colBase + (cc & 1) * 8;
  st_sc128(dst, v);
}

// ---------------- shared GEMM loop: bm-pair stealing, line-merged epilogue ----------
__device__ void gemm_loop(char* pool, int tid,
                          const _Float16* Af, const _Float16* Bw,
                          const float* bias, float* C,
                          unsigned* flags, unsigned* tcnt) {
  _Float16* lsA0 = (_Float16*)pool;
  _Float16* lsA1 = lsA0 + 128 * 64;
  _Float16* lsB  = lsA1 + 128 * 64;
  volatile int* bc = (volatile int*)(pool + 49152);
  const int wave = tid >> 6, lane = tid & 63, l15 = lane & 15, lq = lane >> 4;
  const int wr = (wave >> 2) * 64, wc = (wave & 3) * 32;
  unsigned lastR = 0;
  __syncthreads();
  for (;;) {
    if (tid == 0)
      *bc = (int)__hip_atomic_fetch_add(tcnt, 1u, __ATOMIC_RELAXED,
                                        __HIP_MEMORY_SCOPE_AGENT);
    __syncthreads();
    const int pr = *bc;
    __syncthreads();
    if (pr >= NPAIR) break;
    const int p = pr / 250, bn = pr - p * 250;
    const unsigned Rneed = 4u * (unsigned)p + 4u;   // X1f16 t up to 4p+3
    if (lastR < Rneed) {
      {
        const unsigned* fp = &flags[(size_t)((80 + (lane >> 3)) * 8 + (lane & 7)) * 32];
        while (!__all((int)(ld_sc32u(fp) >= Rneed))) __builtin_amdgcn_s_sleep(8);
      }
      {
        const unsigned* fp = &flags[(size_t)((88 + (lane >> 3)) * 8 + (lane & 7)) * 32];
        while (!__all((int)(ld_sc32u(fp) >= Rneed))) __builtin_amdgcn_s_sleep(8);
      }
      lastR = Rneed;
    }
    __syncthreads();
    f32x4 acc0[4][2] = {}, acc1[4][2] = {};
    const size_t arow0 = (size_t)p * 256;
    const size_t brow0 = (size_t)bn * 128;
    for (int kb = 0; kb < 512; kb += 64) {
#pragma unroll
      for (int i = 0; i < 2; ++i) {
        int c = tid + i * 512;
        int row = c >> 3, kc = (c & 7) * 8;
        int el = (row * 64 + kc) ^ ((row & 7) << 3);
        *(f16x8*)&lsA0[el] = *(const f16x8*)(Af + (arow0 + row) * 512 + kb + kc);
        *(f16x8*)&lsA1[el] = *(const f16x8*)(Af + (arow0 + 128 + row) * 512 + kb + kc);
        *(f16x8*)&lsB[el]  = *(const f16x8*)(Bw + (brow0 + row) * 512 + kb + kc);
      }
      __syncthreads();
#pragma unroll
      for (int k0 = 0; k0 < 64; k0 += 32) {
        const int kk = k0 + lq * 8;
        f16x8 af0[4], af1[4], bfr[2];
#pragma unroll
        for (int i = 0; i < 4; ++i) {
          int ra = wr + i * 16 + l15;
          int el = (ra * 64 + kk) ^ ((ra & 7) << 3);
          af0[i] = *(const f16x8*)&lsA0[el];
          af1[i] = *(const f16x8*)&lsA1[el];
        }
#pragma unroll
        for (int jt = 0; jt < 2; ++jt) {
          int rb = wc + jt * 16 + l15;
          bfr[jt] = *(const f16x8*)&lsB[(rb * 64 + kk) ^ ((rb & 7) << 3)];
        }
#pragma unroll
        for (int i = 0; i < 4; ++i)
#pragma unroll
          for (int jt = 0; jt < 2; ++jt) {
            acc0[i][jt] = mma_f16(af0[i], bfr[jt], acc0[i][jt]);
            acc1[i][jt] = mma_f16(af1[i], bfr[jt], acc1[i][jt]);
          }
      }
      __syncthreads();
    }
    const float b0v = bias[brow0 + wc + l15];
    const float b1v = bias[brow0 + wc + 16 + l15];
#pragma unroll
    for (int i = 0; i < 4; ++i) {
#pragma unroll
      for (int r = 0; r < 4; ++r) {
        const size_t row = arow0 + wr + i * 16 + lq * 4 + r;
        float* pa = C + row * (size_t)NV + brow0 + wc + l15;
        st_nt(pa, acc0[i][0][r] + b0v);
        st_nt(pa + 16, acc0[i][1][r] + b1v);
        float* pb = pa + (size_t)128 * NV;
        st_nt(pb, acc1[i][0][r] + b0v);
        st_nt(pb + 16, acc1[i][1][r] + b1v);
      }
    }
  }
}

// ================= fused persistent kernel (wave-autonomous recurrence) ==========
__launch_bounds__(512, 1)
__global__ void k_main(
    const float* __restrict__ Wr, const float* __restrict__ Wz, const float* __restrict__ Wh,
    const float* __restrict__ Wrb, const float* __restrict__ Wzb, const float* __restrict__ Whb,
    const float* __restrict__ hid,
    const short* __restrict__ XeHi, const short* __restrict__ XeLo,
    short* X1Hi, short* X1Lo, _Float16* X1f16,
    short* h0Hi, short* h0Lo,
    short* rh0Hi, short* rh0Lo, short* rh1Hi, short* rh1Lo,
    float* z0, float* z1, float* hidOut,
    const _Float16* OWf, const float* outb, float* out,
    unsigned* flags, unsigned* tcnt) {
  __shared__ __align__(16) char pool[147456];
  short* lsHi = (short*)pool;                  // 64 KB weights hi
  short* lsLo = lsHi + 32 * 1024;              // 64 KB weights lo
  char* wscrBase = pool + 131072;              // 16 KB: 2 KB per-wave scratch

  const int wg = blockIdx.x;
  const int tid = threadIdx.x;
  const int wave = tid >> 6, lane = tid & 63, l15 = lane & 15, lq = lane >> 4;
  const int ct = wave >> 2, rt = wave & 3;     // col-tile, row-tile of this wave
  const int r0 = rt * 16 + l15;                // act row for MMA A-frag
  short* scrH = (short*)(wscrBase + wave * 2048);
  short* scrL = scrH + 256;
  _Float16* scrX = (_Float16*)(scrH + 512);
  float* scrF = (float*)scrH;

  if (wg < 64) {
    // ===== A classes: gates. 64 rows x 32 gate-cols per wg =====
    const bool isL1 = (wg >= 32);
    const int cg = isL1 ? (wg - 32) : wg;
    const int jc = cg * 32;
    const bool isR = (cg < 16);
    const int wrow = ct * 16 + l15;            // weight row within wg slice
    stage_weights(lsHi, lsLo, Wr + (isL1 ? (size_t)512 * 1024 : 0),
                  Wz + (isL1 ? (size_t)512 * 1024 : 0), jc, tid);
    float bv;
    {
      const int j = jc + ct * 16 + l15;
      bv = (j < 512) ? Wrb[(isL1 ? 512 : 0) + j] : Wzb[(isL1 ? 512 : 0) + j - 512];
    }
    short* outHi = isL1 ? rh1Hi : rh0Hi;
    short* outLo = isL1 ? rh1Lo : rh0Lo;
    float* outZ  = isL1 ? z1 : z0;
    __syncthreads();                            // weights staged (only barrier)
    for (int t = 0; t < NT; ++t) {
      f32x4 accH[2] = {}, accL[2] = {};
      const short *hH, *hL;
      if (!isL1) {
        // static x-half first (pre-wait, hidden under producer phase)
        waveMMA16(XeHi + (size_t)t * SZ_H, XeLo + (size_t)t * SZ_H,
                  r0, 0, lsHi, lsLo, wrow, accH, accL, lq);
        // poll l0B producer WAVES: rows rt, all 16 wgs x 2 col-tiles, thr t
        {
          const unsigned* fp; unsigned thr;
          if (lane < 32) {
            const int bb = lane >> 1, ctp = lane & 1;
            fp = &flags[(size_t)((64 + bb) * 8 + ctp * 4 + rt) * 32]; thr = (unsigned)t;
          } else { fp = flags; thr = 0u; }
          wave_poll(fp, thr);
        }
        hH = h0Hi + (size_t)t * SZ_H; hL = h0Lo + (size_t)t * SZ_H;
      } else {
        // poll: lanes 0-31 l0B thr t+1 (x1=h0(t+1)); lanes 32-63 l1B thr t (h1(t))
        {
          const unsigned* fp; unsigned thr;
          if (lane < 32) {
            const int bb = lane >> 1, ctp = lane & 1;
            fp = &flags[(size_t)((64 + bb) * 8 + ctp * 4 + rt) * 32]; thr = (unsigned)(t + 1);
          } else {
            const int li = lane - 32, bb = li >> 1, ctp = li & 1;
            fp = &flags[(size_t)((80 + bb) * 8 + ctp * 4 + rt) * 32]; thr = (unsigned)t;
          }
          wave_poll(fp, thr);
        }
        hH = X1Hi + (size_t)t * SZ_H; hL = X1Lo + (size_t)t * SZ_H;
      }
      // epilogue h-values (r-wgs): issue loads now, consume after MMA
      float hv[4];
      if (isR) {
#pragma unroll
        for (int r = 0; r < 4; ++r) {
          const int row = rt * 16 + lq * 4 + r, col = jc + ct * 16 + l15;
          hv[r] = bf2f((unsigned short)hH[row * 512 + col]) +
                  bf2f((unsigned short)hL[row * 512 + col]);
        }
      }
      if (!isL1) {
        waveMMA16(hH, hL, r0, 512, lsHi, lsLo, wrow, accH, accL, lq);   // dependent h-half
      } else {
        waveMMA16(h0Hi + (size_t)(t + 1) * SZ_H, h0Lo + (size_t)(t + 1) * SZ_H,
                  r0, 0, lsHi, lsLo, wrow, accH, accL, lq);             // x1-half
        waveMMA16(hH, hL, r0, 512, lsHi, lsLo, wrow, accH, accL, lq);   // h1-half
      }
      f32x4 acc = accH[0] + accH[1] + accL[0] + accL[1];
      if (isR) {
#pragma unroll
        for (int r = 0; r < 4; ++r) {
          const float s = fast_sigmoid(acc[r] + bv);
          short hi, lo; split2(s * hv[r], &hi, &lo);
          scrH[(lq * 4 + r) * 16 + l15] = hi;
          scrL[(lq * 4 + r) * 16 + l15] = lo;
        }
        wave_store16(scrH, scrL, outHi + (size_t)t * SZ_H, outLo + (size_t)t * SZ_H,
                     rt, jc + ct * 16, lane);
      } else {
#pragma unroll
        for (int r = 0; r < 4; ++r)
          scrF[(lq * 4 + r) * 16 + l15] = fast_sigmoid(acc[r] + bv);
        asm volatile("s_waitcnt lgkmcnt(0)" ::: "memory");
        const int rr = lane >> 2, cc = lane & 3;
        f32x4 v = *(const f32x4*)&scrF[rr * 16 + cc * 4];
        st_sc128(outZ + (size_t)t * SZ_H + (size_t)(rt * 16 + rr) * 512 +
                 (jc - 512) + ct * 16 + cc * 4, __builtin_bit_cast(i32x4, v));
      }
      wpublish(flags, wg * 8 + wave, (unsigned)(t + 1), lane);
    }
  } else if (wg < 96) {
    // ===== B classes: candidate + state. 64 rows x 32 h-cols per wg =====
    const bool isL1 = (wg >= 80);
    const int b = isL1 ? (wg - 80) : (wg - 64);
    const int jc = b * 32;
    const int layer = isL1 ? 1 : 0;
    const int wrow = ct * 16 + l15;
    stage_weights(lsHi, lsLo, Wh + (size_t)layer * 512 * 1024, nullptr, jc, tid);
    const float bv = Whb[layer * 512 + jc + ct * 16 + l15];
    // register-carried hidden state (exact fp32 from input)
    f32x4 hOld;
#pragma unroll
    for (int r = 0; r < 4; ++r)
      hOld[r] = hid[(size_t)layer * SZ_H + (size_t)(rt * 16 + lq * 4 + r) * 512 +
                    jc + ct * 16 + l15];
    short* myHi = isL1 ? X1Hi : h0Hi;
    short* myLo = isL1 ? X1Lo : h0Lo;
    const short* rhHi_ = isL1 ? rh1Hi : rh0Hi;
    const short* rhLo_ = isL1 ? rh1Lo : rh0Lo;
    const float* zArr = isL1 ? z1 : z0;
    __syncthreads();                            // weights staged (only barrier)
    for (int t = 0; t < NT; ++t) {
      f32x4 accH[2] = {}, accL[2] = {};
      if (!isL1) {
        // static x-half (pre-wait)
        waveMMA16(XeHi + (size_t)t * SZ_H, XeLo + (size_t)t * SZ_H,
                  r0, 0, lsHi, lsLo, wrow, accH, accL, lq);
        // poll: lanes 0-31 l0A r-wave flags thr t+1; lane 32 z-wg wave thr t+1
        {
          const unsigned* fp; unsigned thr = (unsigned)(t + 1);
          if (lane < 32) {
            const int cgp = lane >> 1, ctp = lane & 1;
            fp = &flags[(size_t)(cgp * 8 + ctp * 4 + rt) * 32];
          } else if (lane == 32) {
            fp = &flags[(size_t)((16 + b) * 8 + ct * 4 + rt) * 32];
          } else { fp = flags; thr = 0u; }
          wave_poll(fp, thr);
        }
      } else {
        // stage 1: poll l0B thr t+1, compute x1-half
        {
          const unsigned* fp; unsigned thr;
          if (lane < 32) {
            const int bb = lane >> 1, ctp = lane & 1;
            fp = &flags[(size_t)((64 + bb) * 8 + ctp * 4 + rt) * 32]; thr = (unsigned)(t + 1);
          } else { fp = flags; thr = 0u; }
          wave_poll(fp, thr);
        }
        waveMMA16(h0Hi + (size_t)(t + 1) * SZ_H, h0Lo + (size_t)(t + 1) * SZ_H,
                  r0, 0, lsHi, lsLo, wrow, accH, accL, lq);
        // stage 2: poll l1A r-waves thr t+1; lane 32 z1 wave thr t+1
        {
          const unsigned* fp; unsigned thr = (unsigned)(t + 1);
          if (lane < 32) {
            const int cgp = lane >> 1, ctp = lane & 1;
            fp = &flags[(size_t)((32 + cgp) * 8 + ctp * 4 + rt) * 32];
          } else if (lane == 32) {
            fp = &flags[(size_t)((48 + b) * 8 + ct * 4 + rt) * 32];
          } else { fp = flags; thr = 0u; }
          wave_poll(fp, thr);
        }
      }
      // z reads (producer confirmed): 4 scalar f32, issue before rh-MMA
      float zv[4];
#pragma unroll
      for (int r = 0; r < 4; ++r)
        zv[r] = zArr[(size_t)t * SZ_H + (size_t)(rt * 16 + lq * 4 + r) * 512 +
                     jc + ct * 16 + l15];
      // dependent rh-half
      waveMMA16(rhHi_ + (size_t)t * SZ_H, rhLo_ + (size_t)t * SZ_H,
                r0, 512, lsHi, lsLo, wrow, accH, accL, lq);
      f32x4 acc = accH[0] + accH[1] + accL[0] + accL[1];
      f32x4 hnew;
#pragma unroll
      for (int r = 0; r < 4; ++r) {
        const float hh = fast_tanh(acc[r] + bv);
        const float hn = (1.0f - zv[r]) * hOld[r] + zv[r] * hh;
        hnew[r] = hn;
        short hi, lo; split2(hn, &hi, &lo);
        scrH[(lq * 4 + r) * 16 + l15] = hi;
        scrL[(lq * 4 + r) * 16 + l15] = lo;
        if (isL1) scrX[(lq * 4 + r) * 16 + l15] = (_Float16)hn;
        if (t == NT - 1)
          hidOut[(size_t)layer * SZ_H + (size_t)(rt * 16 + lq * 4 + r) * 512 +
                 jc + ct * 16 + l15] = hn;
      }
      hOld = hnew;
      wave_store16(scrH, scrL, myHi + (size_t)(t + 1) * SZ_H, myLo + (size_t)(t + 1) * SZ_H,
                   rt, jc + ct * 16, lane);
      if (isL1 && lane < 32) {
        const int rr = lane >> 1, cc = lane & 1;
        i32x4 v = *(const i32x4*)&scrX[rr * 16 + cc * 8];
        st_sc128(X1f16 + (size_t)t * SZ_H + (size_t)(rt * 16 + rr) * 512 +
                 jc + ct * 16 + cc * 8, v);
      }
      wpublish(flags, wg * 8 + wave, (unsigned)(t + 1), lane);
    }
  }
  // ===== everyone converges on the GEMM (dedicated wgs 96..255 start now) =====
  gemm_loop(pool, tid, X1f16, OWf, outb, out, flags, tcnt);
}

// ---------------- launcher ----------------
extern "C" void kernel_launch(void* const* d_in, const int* in_sizes, int n_in,
                              void* d_out, int out_size, void* d_ws, size_t ws_size,
                              hipStream_t stream) {
  (void)in_sizes; (void)n_in; (void)out_size; (void)ws_size;
  const int*   toks = (const int*)d_in[0];
  const float* hid  = (const float*)d_in[1];
  const float* emb  = (const float*)d_in[2];
  const float* Wr   = (const float*)d_in[3];
  const float* Wrb  = (const float*)d_in[4];
  const float* Wz   = (const float*)d_in[5];
  const float* Wzb  = (const float*)d_in[6];
  const float* Wh   = (const float*)d_in[7];
  const float* Whb  = (const float*)d_in[8];
  const float* outw = (const float*)d_in[9];
  const float* outb = (const float*)d_in[10];
  float* out = (float*)d_out;

  char* base = (char*)d_ws;
  size_t off = 0;
  auto carve = [&](size_t bytes) -> char* {
    char* r = base + off;
    off = (off + bytes + 255) & ~(size_t)255;
    return r;
  };
  _Float16* OWf   = (_Float16*)carve(SZ_OW * 2);
  short*    XeHi  = (short*)carve(SZ_XE * 2);
  short*    XeLo  = (short*)carve(SZ_XE * 2);
  short*    X1Hi  = (short*)carve((size_t)(NT + 1) * SZ_H * 2);
  short*    X1Lo  = (short*)carve((size_t)(NT + 1) * SZ_H * 2);
  _Float16* X1f16 = (_Float16*)carve((size_t)NT * SZ_H * 2);
  short*    h0Hi  = (short*)carve((size_t)(NT + 1) * SZ_H * 2);
  short*    h0Lo  = (short*)carve((size_t)(NT + 1) * SZ_H * 2);
  short*    rh0Hi = (short*)carve((size_t)NT * SZ_H * 2);
  short*    rh0Lo = (short*)carve((size_t)NT * SZ_H * 2);
  short*    rh1Hi = (short*)carve((size_t)NT * SZ_H * 2);
  short*    rh1Lo = (short*)carve((size_t)NT * SZ_H * 2);
  float*    z0    = (float*)carve((size_t)NT * SZ_H * 4);
  float*    z1    = (float*)carve((size_t)NT * SZ_H * 4);
  unsigned* flags = (unsigned*)carve(98304);   // 768 wave-slots * 128B
  unsigned* tcnt  = (unsigned*)carve(256);

  hipMemsetAsync(flags, 0, 98304, stream);
  hipMemsetAsync(tcnt, 0, 256, stream);

  k_prep<<<2048, 256, 0, stream>>>(outw, toks, emb, hid,
                                   OWf, XeHi, XeLo, X1Hi, X1Lo, h0Hi, h0Lo);

  k_main<<<256, 512, 0, stream>>>(
      Wr, Wz, Wh, Wrb, Wzb, Whb, hid, XeHi, XeLo,
      X1Hi, X1Lo, X1f16, h0Hi, h0Lo,
      rh0Hi, rh0Lo, rh1Hi, rh1Lo, z0, z1,
      out + LOGITS, OWf, outb, out, flags, tcnt);
}